// Round 1
// baseline (226.444 us; speedup 1.0000x reference)
//
#include <hip/hip_runtime.h>

#define DIM   128
#define DMASK 127
#define PLANE (DIM * DIM)     // 16384
#define VOX   (1 << 21)       // 128^3
#define NCH   12

// De-aliased layout (validated r12: 199->142 us): channel stride 4MB+4KB,
// image stride +2KB more. Keeps the 24 stream bases off one channel slot.
#define CHS   (VOX + 2048)
#define IMGS  (NCH * CHS + 1024)

typedef __attribute__((ext_vector_type(2))) _Float16 half2v;
typedef __attribute__((ext_vector_type(4))) _Float16 half4v;

// Per-channel shift pairs (d,h,w) = 2*(one_hot_idx - 1); verified (absmax 0).
__constant__ int c_sd1[12] = { 0, 0, 0, 0, 0, 2, 2, 2, 0, 0, 0, 0};
__constant__ int c_sh1[12] = { 0,-2,-2, 0, 0, 0, 0, 0, 2, 2, 2, 2};
__constant__ int c_sw1[12] = {-2, 0, 0, 2, 2, 0, 0, 0, 0, 0, 0, 0};
__constant__ int c_sd2[12] = {-2,-2, 0,-2, 0, 0, 0, 0,-2, 0, 0, 2};
__constant__ int c_sh2[12] = { 0, 0, 0, 0,-2, 0,-2, 0, 0, 0, 0, 0};
__constant__ int c_sw2[12] = { 0, 0,-2, 0, 0,-2, 0, 2, 0,-2, 2, 0};

__device__ __forceinline__ int clamp7(int v) { return min(max(v, 0), DMASK); }

// F123 v6: WAVE-AUTONOMOUS, FINER D-SEGS. Each wave owns (ch, 8-row h-slice,
// 8-plane d-seg) -> 3072 tasks/image (was 1536), grid 1536 blocks = 6/CU
// submitted, 4 resident (VGPR quantum at 84 regs) vs 3 before. Theory (r0):
// latency-bound at 48% VALUBusy / 24.7% occupancy, grid-limited to 3
// blocks/CU. +20% halo work along D traded for +33% resident waves.
// W-box via lane shuffles (+/-1 lane = +/-2 cols), H-box via register
// sliding sums, D-box via register window. ZERO LDS, ZERO __syncthreads.

// One input-plane iteration. S5C must be a compile-time constant after
// unrolling (static hist indexing; runtime index -> scratch, rule #20).
#define PLANE_ITER(IT_EXPR, S5C)                                             \
    {                                                                        \
        int it = (IT_EXPR);                                                  \
        int dp = clamp7(d0 - 2 + it);                                        \
        int pOffA = clamp7(dp + sd1) * (PLANE * 4);                          \
        int pOffB = clamp7(dp + sd2) * (PLANE * 4);                          \
        float tX[12], tY[12];                                                \
        _Pragma("unroll")                                                    \
        for (int r = 0; r < 12; ++r) {                                       \
            float2 a = *(const float2*)(imgc + (pOffA + rowOffA[r] + colA)); \
            float2 b = *(const float2*)(imgc + (pOffB + rowOffB[r] + colB)); \
            a.y = fixAlo ? a.x : a.y;  a.x = fixAhi ? a.y : a.x;             \
            b.y = fixBlo ? b.x : b.y;  b.x = fixBhi ? b.y : b.x;             \
            float dx = a.x - b.x; dx *= dx;      /* D2[2l]   */              \
            float dy = a.y - b.y; dy *= dy;      /* D2[2l+1] */              \
            float lx = __shfl_up(dx, 1, 64);     /* D2[2l-2] */              \
            float ly = __shfl_up(dy, 1, 64);     /* D2[2l-1] */              \
            float rx = __shfl_down(dx, 1, 64);   /* D2[2l+2] */              \
            float ry = __shfl_down(dy, 1, 64);   /* D2[2l+3] */              \
            ly = (l == 0)  ? dx : ly;            /* D2[-1 -> 0]    */        \
            rx = (l == 63) ? dy : rx;            /* D2[128 -> 127] */        \
            tX[r] = lx + ly + dx + dy + rx;      /* W-box(2l)   */           \
            tY[r] = ly + dx + dy + rx + ry;      /* W-box(2l+1) */           \
        }                                                                    \
        float sx = tX[0] + tX[1] + tX[2] + tX[3] + tX[4];                    \
        float sy = tY[0] + tY[1] + tY[2] + tY[3] + tY[4];                    \
        bool dowrite = (it >= 4);                                            \
        _Float16* dstD = dstBase + (size_t)(d0 + it - 4) * PLANE;            \
        _Pragma("unroll")                                                    \
        for (int k = 0; k < 8; ++k) {                                        \
            half2v hv = { (_Float16)sx, (_Float16)sy }; /* round first */    \
            half2v old = hist[S5C][k];                                       \
            win[k].x += (float)hv[0] - (float)old[0];                        \
            win[k].y += (float)hv[1] - (float)old[1];                        \
            hist[S5C][k] = hv;                                               \
            if (dowrite) {                                                   \
                half2v ov = { (_Float16)win[k].x, (_Float16)win[k].y };      \
                *(half2v*)(dstD + k * DIM) = ov;                             \
            }                                                                \
            if (k < 7) {                                                     \
                sx += tX[k + 5] - tX[k];                                     \
                sy += tY[k + 5] - tY[k];                                     \
            }                                                                \
        }                                                                    \
    }

__global__ __launch_bounds__(256, 4) void f123(const float* __restrict__ img0,
                                               const float* __restrict__ img1,
                                               _Float16* __restrict__ Sall) {
    const float* img = blockIdx.y ? img1 : img0;
    _Float16* outS = Sall + (size_t)blockIdx.y * IMGS;
    const char* imgc = (const char*)img;

    int wid = (blockIdx.x << 2) + (threadIdx.x >> 6);  // 0..3071
    int ch = wid >> 8;                 // 12 channels
    int hs = (wid >> 4) & 15;          // 16 h-slices of 8 rows
    int ds = wid & 15;                 // 16 d-segs of 8 planes
    int h0 = hs << 3;
    int d0 = ds << 3;
    int l  = threadIdx.x & 63;

    int sd1 = c_sd1[ch], sh1 = c_sh1[ch], sw1 = c_sw1[ch];
    int sd2 = c_sd2[ch], sh2 = c_sh2[ch], sw2 = c_sw2[ch];

    // wave-uniform row byte-offsets (double clamp composed), 12 rows
    int rowOffA[12], rowOffB[12];
#pragma unroll
    for (int r = 0; r < 12; ++r) {
        int hq = clamp7(h0 - 2 + r);
        rowOffA[r] = clamp7(hq + sh1) * (DIM * 4);
        rowOffB[r] = clamp7(hq + sh2) * (DIM * 4);
    }

    // per-lane column byte bases (float2 at cols 2l+sw, clamped to [0,126])
    int c2 = l << 1;
    int colA = min(max(c2 + sw1, 0), 126) * 4;
    int colB = min(max(c2 + sw2, 0), 126) * 4;
    bool fixAlo = (sw1 < 0) && (l == 0);   // need (v0,v0): a.y = a.x
    bool fixAhi = (sw1 > 0) && (l == 63);  // need (v127,v127): a.x = a.y
    bool fixBlo = (sw2 < 0) && (l == 0);
    bool fixBhi = (sw2 > 0) && (l == 63);

    float2 win[8];
    half2v hist[5][8];
#pragma unroll
    for (int k = 0; k < 8; ++k) {
        win[k].x = 0.0f; win[k].y = 0.0f;
#pragma unroll
        for (int s = 0; s < 5; ++s) hist[s][k] = half2v{(_Float16)0.0f, (_Float16)0.0f};
    }

    _Float16* dstBase = outS + (size_t)ch * CHS + h0 * DIM + c2;

    // 12 input planes per task: 2 prologue (s5 = 0,1) + 2 x 5 with the
    // ring pattern (2,3,4,0,1) == (2+j)%5, matching it%5 for it = 2+5*oo+j.
#pragma unroll
    for (int j = 0; j < 2; ++j)
        PLANE_ITER(j, j)

    for (int oo = 0; oo < 2; ++oo) {
#pragma unroll
        for (int j = 0; j < 5; ++j)
            PLANE_ITER(2 + oo * 5 + j, ((2 + j) % 5))
    }
}

// kmse v6 (unchanged, validated r12): 4 vox/thread, 24 independent 8-B
// loads, all-register, no atomics, de-aliased CHS stride.
__global__ __launch_bounds__(256, 3) void kmse(const _Float16* __restrict__ S0,
                                               const _Float16* __restrict__ S1,
                                               float* __restrict__ partial) {
    int t = blockIdx.x * 256 + threadIdx.x;       // 2048 blocks

    half4v v0[NCH], v1[NCH];
#pragma unroll
    for (int ch = 0; ch < NCH; ++ch)
        v0[ch] = ((const half4v*)(S0 + (size_t)ch * CHS))[t];
#pragma unroll
    for (int ch = 0; ch < NCH; ++ch)
        v1[ch] = ((const half4v*)(S1 + (size_t)ch * CHS))[t];

    float mn0[4], sm0[4], mn1[4], sm1[4];
#pragma unroll
    for (int j = 0; j < 4; ++j) {
        mn0[j] = 3.4e38f; sm0[j] = 0.0f;
        mn1[j] = 3.4e38f; sm1[j] = 0.0f;
    }
#pragma unroll
    for (int ch = 0; ch < NCH; ++ch)
#pragma unroll
        for (int j = 0; j < 4; ++j) {
            float s0 = (float)v0[ch][j];
            float s1 = (float)v1[ch][j];
            mn0[j] = fminf(mn0[j], s0); sm0[j] += s0;
            mn1[j] = fminf(mn1[j], s1); sm1[j] += s1;
        }

    float inv0[4], inv1[4];
#pragma unroll
    for (int j = 0; j < 4; ++j) {
        inv0[j] = __fdividef(1.0f, sm0[j] * (1.0f / 12.0f) - mn0[j]);
        inv1[j] = __fdividef(1.0f, sm1[j] * (1.0f / 12.0f) - mn1[j]);
    }

    float acc = 0.0f;
#pragma unroll
    for (int ch = 0; ch < NCH; ++ch)
#pragma unroll
        for (int j = 0; j < 4; ++j) {
            float e0 = __expf(-((float)v0[ch][j] - mn0[j]) * inv0[j]);
            float e1 = __expf(-((float)v1[ch][j] - mn1[j]) * inv1[j]);
            float df = e0 - e1;
            acc += df * df;
        }

#pragma unroll
    for (int off = 32; off > 0; off >>= 1)
        acc += __shfl_down(acc, off, 64);
    __shared__ float smem[4];
    int lane = threadIdx.x & 63, wv = threadIdx.x >> 6;
    if (lane == 0) smem[wv] = acc;
    __syncthreads();
    if (threadIdx.x == 0)
        partial[blockIdx.x] = smem[0] + smem[1] + smem[2] + smem[3];
}

// kred: sum 2048 partials, write the final scalar.
__global__ __launch_bounds__(256) void kred(const float* __restrict__ partial,
                                            float* __restrict__ out) {
    int tid = threadIdx.x;
    float acc = 0.0f;
#pragma unroll
    for (int k = 0; k < 8; ++k)
        acc += partial[tid + (k << 8)];
#pragma unroll
    for (int off = 32; off > 0; off >>= 1)
        acc += __shfl_down(acc, off, 64);
    __shared__ float smem[4];
    int lane = tid & 63, wv = tid >> 6;
    if (lane == 0) smem[wv] = acc;
    __syncthreads();
    if (tid == 0)
        out[0] = (smem[0] + smem[1] + smem[2] + smem[3])
               * (1.0f / (12.0f * (float)VOX));
}

__global__ void kdiag(float* out, float ws_mb) { out[0] = ws_mb; }

extern "C" void kernel_launch(void* const* d_in, const int* in_sizes, int n_in,
                              void* d_out, int out_size, void* d_ws, size_t ws_size,
                              hipStream_t stream) {
    const float* y_true = (const float*)d_in[0];
    const float* y_pred = (const float*)d_in[1];
    float* out = (float*)d_out;

    const size_t NEED = 2ull * IMGS * sizeof(_Float16) + 8192 + 64;  // ~96.2 MB
    if (ws_size < NEED) {
        kdiag<<<1, 1, 0, stream>>>(out, (float)(ws_size >> 20));
        return;
    }

    _Float16* S0      = (_Float16*)d_ws;            // ssd img0 (padded layout)
    _Float16* S1      = S0 + (size_t)IMGS;          // ssd img1
    float*    partial = (float*)(S1 + (size_t)IMGS);// 2048 floats

    // 3072 wave-tasks per image (12 ch x 16 hslices x 16 dsegs), 4 waves/block
    f123<<<dim3(768, 2), 256, 0, stream>>>(y_true, y_pred, S0);
    kmse<<<VOX / 4 / 256, 256, 0, stream>>>(S0, S1, partial);
    kred<<<1, 256, 0, stream>>>(partial, out);
}

// Round 3
// 158.810 us; speedup vs baseline: 1.4259x; 1.4259x over previous
//
#include <hip/hip_runtime.h>

#define DIM   128
#define DMASK 127
#define PLANE (DIM * DIM)     // 16384
#define VOX   (1 << 21)       // 128^3
#define NCH   12

// De-aliased layout (validated r12: 199->142 us): channel stride 4MB+4KB,
// image stride +2KB more. Keeps the 24 stream bases off one channel slot.
#define CHS   (VOX + 2048)
#define IMGS  (NCH * CHS + 1024)

typedef __attribute__((ext_vector_type(2))) _Float16 half2v;
typedef __attribute__((ext_vector_type(4))) _Float16 half4v;

// Per-channel shift pairs (d,h,w) = 2*(one_hot_idx - 1); verified (absmax 0).
__constant__ int c_sd1[12] = { 0, 0, 0, 0, 0, 2, 2, 2, 0, 0, 0, 0};
__constant__ int c_sh1[12] = { 0,-2,-2, 0, 0, 0, 0, 0, 2, 2, 2, 2};
__constant__ int c_sw1[12] = {-2, 0, 0, 2, 2, 0, 0, 0, 0, 0, 0, 0};
__constant__ int c_sd2[12] = {-2,-2, 0,-2, 0, 0, 0, 0,-2, 0, 0, 2};
__constant__ int c_sh2[12] = { 0, 0, 0, 0,-2, 0,-2, 0, 0, 0, 0, 0};
__constant__ int c_sw2[12] = { 0, 0,-2, 0, 0,-2, 0, 2, 0,-2, 2, 0};

__device__ __forceinline__ int clamp7(int v) { return min(max(v, 0), DMASK); }

// F123 v7: WAVE-AUTONOMOUS, FINER D-SEGS, NO VGPR CAP. Each wave owns
// (ch, 8-row h-slice, 8-plane d-seg) -> 3072 tasks/image, grid 1536 blocks.
// r1 LESSON: __launch_bounds__(256,4) clamped to 64 VGPR -> spilled the
// ~56-reg live state (FETCH 23->221 MB, WRITE +236 MB, dur 66->160 us).
// At the natural ~84 VGPR the HW quantum (64/128/256 steps) already gives
// 4 waves/SIMD = 4 blocks/CU resident; the finer grid alone supplies the
// occupancy. Keep (256,3) which is known spill-free from r0.
// (r2 was an infra failure — this source resubmitted unchanged.)
// W-box via lane shuffles (+/-1 lane = +/-2 cols), H-box via register
// sliding sums, D-box via register window. ZERO LDS, ZERO __syncthreads.

// One input-plane iteration. S5C must be a compile-time constant after
// unrolling (static hist indexing; runtime index -> scratch, rule #20).
#define PLANE_ITER(IT_EXPR, S5C)                                             \
    {                                                                        \
        int it = (IT_EXPR);                                                  \
        int dp = clamp7(d0 - 2 + it);                                        \
        int pOffA = clamp7(dp + sd1) * (PLANE * 4);                          \
        int pOffB = clamp7(dp + sd2) * (PLANE * 4);                          \
        float tX[12], tY[12];                                                \
        _Pragma("unroll")                                                    \
        for (int r = 0; r < 12; ++r) {                                       \
            float2 a = *(const float2*)(imgc + (pOffA + rowOffA[r] + colA)); \
            float2 b = *(const float2*)(imgc + (pOffB + rowOffB[r] + colB)); \
            a.y = fixAlo ? a.x : a.y;  a.x = fixAhi ? a.y : a.x;             \
            b.y = fixBlo ? b.x : b.y;  b.x = fixBhi ? b.y : b.x;             \
            float dx = a.x - b.x; dx *= dx;      /* D2[2l]   */              \
            float dy = a.y - b.y; dy *= dy;      /* D2[2l+1] */              \
            float lx = __shfl_up(dx, 1, 64);     /* D2[2l-2] */              \
            float ly = __shfl_up(dy, 1, 64);     /* D2[2l-1] */              \
            float rx = __shfl_down(dx, 1, 64);   /* D2[2l+2] */              \
            float ry = __shfl_down(dy, 1, 64);   /* D2[2l+3] */              \
            ly = (l == 0)  ? dx : ly;            /* D2[-1 -> 0]    */        \
            rx = (l == 63) ? dy : rx;            /* D2[128 -> 127] */        \
            tX[r] = lx + ly + dx + dy + rx;      /* W-box(2l)   */           \
            tY[r] = ly + dx + dy + rx + ry;      /* W-box(2l+1) */           \
        }                                                                    \
        float sx = tX[0] + tX[1] + tX[2] + tX[3] + tX[4];                    \
        float sy = tY[0] + tY[1] + tY[2] + tY[3] + tY[4];                    \
        bool dowrite = (it >= 4);                                            \
        _Float16* dstD = dstBase + (size_t)(d0 + it - 4) * PLANE;            \
        _Pragma("unroll")                                                    \
        for (int k = 0; k < 8; ++k) {                                        \
            half2v hv = { (_Float16)sx, (_Float16)sy }; /* round first */    \
            half2v old = hist[S5C][k];                                       \
            win[k].x += (float)hv[0] - (float)old[0];                        \
            win[k].y += (float)hv[1] - (float)old[1];                        \
            hist[S5C][k] = hv;                                               \
            if (dowrite) {                                                   \
                half2v ov = { (_Float16)win[k].x, (_Float16)win[k].y };      \
                *(half2v*)(dstD + k * DIM) = ov;                             \
            }                                                                \
            if (k < 7) {                                                     \
                sx += tX[k + 5] - tX[k];                                     \
                sy += tY[k + 5] - tY[k];                                     \
            }                                                                \
        }                                                                    \
    }

__global__ __launch_bounds__(256, 3) void f123(const float* __restrict__ img0,
                                               const float* __restrict__ img1,
                                               _Float16* __restrict__ Sall) {
    const float* img = blockIdx.y ? img1 : img0;
    _Float16* outS = Sall + (size_t)blockIdx.y * IMGS;
    const char* imgc = (const char*)img;

    int wid = (blockIdx.x << 2) + (threadIdx.x >> 6);  // 0..3071
    int ch = wid >> 8;                 // 12 channels
    int hs = (wid >> 4) & 15;          // 16 h-slices of 8 rows
    int ds = wid & 15;                 // 16 d-segs of 8 planes
    int h0 = hs << 3;
    int d0 = ds << 3;
    int l  = threadIdx.x & 63;

    int sd1 = c_sd1[ch], sh1 = c_sh1[ch], sw1 = c_sw1[ch];
    int sd2 = c_sd2[ch], sh2 = c_sh2[ch], sw2 = c_sw2[ch];

    // wave-uniform row byte-offsets (double clamp composed), 12 rows
    int rowOffA[12], rowOffB[12];
#pragma unroll
    for (int r = 0; r < 12; ++r) {
        int hq = clamp7(h0 - 2 + r);
        rowOffA[r] = clamp7(hq + sh1) * (DIM * 4);
        rowOffB[r] = clamp7(hq + sh2) * (DIM * 4);
    }

    // per-lane column byte bases (float2 at cols 2l+sw, clamped to [0,126])
    int c2 = l << 1;
    int colA = min(max(c2 + sw1, 0), 126) * 4;
    int colB = min(max(c2 + sw2, 0), 126) * 4;
    bool fixAlo = (sw1 < 0) && (l == 0);   // need (v0,v0): a.y = a.x
    bool fixAhi = (sw1 > 0) && (l == 63);  // need (v127,v127): a.x = a.y
    bool fixBlo = (sw2 < 0) && (l == 0);
    bool fixBhi = (sw2 > 0) && (l == 63);

    float2 win[8];
    half2v hist[5][8];
#pragma unroll
    for (int k = 0; k < 8; ++k) {
        win[k].x = 0.0f; win[k].y = 0.0f;
#pragma unroll
        for (int s = 0; s < 5; ++s) hist[s][k] = half2v{(_Float16)0.0f, (_Float16)0.0f};
    }

    _Float16* dstBase = outS + (size_t)ch * CHS + h0 * DIM + c2;

    // 12 input planes per task: 2 prologue (s5 = 0,1) + 2 x 5 with the
    // ring pattern (2,3,4,0,1) == (2+j)%5, matching it%5 for it = 2+5*oo+j.
#pragma unroll
    for (int j = 0; j < 2; ++j)
        PLANE_ITER(j, j)

    for (int oo = 0; oo < 2; ++oo) {
#pragma unroll
        for (int j = 0; j < 5; ++j)
            PLANE_ITER(2 + oo * 5 + j, ((2 + j) % 5))
    }
}

// kmse v6 (unchanged, validated r12): 4 vox/thread, 24 independent 8-B
// loads, all-register, no atomics, de-aliased CHS stride.
__global__ __launch_bounds__(256, 3) void kmse(const _Float16* __restrict__ S0,
                                               const _Float16* __restrict__ S1,
                                               float* __restrict__ partial) {
    int t = blockIdx.x * 256 + threadIdx.x;       // 2048 blocks

    half4v v0[NCH], v1[NCH];
#pragma unroll
    for (int ch = 0; ch < NCH; ++ch)
        v0[ch] = ((const half4v*)(S0 + (size_t)ch * CHS))[t];
#pragma unroll
    for (int ch = 0; ch < NCH; ++ch)
        v1[ch] = ((const half4v*)(S1 + (size_t)ch * CHS))[t];

    float mn0[4], sm0[4], mn1[4], sm1[4];
#pragma unroll
    for (int j = 0; j < 4; ++j) {
        mn0[j] = 3.4e38f; sm0[j] = 0.0f;
        mn1[j] = 3.4e38f; sm1[j] = 0.0f;
    }
#pragma unroll
    for (int ch = 0; ch < NCH; ++ch)
#pragma unroll
        for (int j = 0; j < 4; ++j) {
            float s0 = (float)v0[ch][j];
            float s1 = (float)v1[ch][j];
            mn0[j] = fminf(mn0[j], s0); sm0[j] += s0;
            mn1[j] = fminf(mn1[j], s1); sm1[j] += s1;
        }

    float inv0[4], inv1[4];
#pragma unroll
    for (int j = 0; j < 4; ++j) {
        inv0[j] = __fdividef(1.0f, sm0[j] * (1.0f / 12.0f) - mn0[j]);
        inv1[j] = __fdividef(1.0f, sm1[j] * (1.0f / 12.0f) - mn1[j]);
    }

    float acc = 0.0f;
#pragma unroll
    for (int ch = 0; ch < NCH; ++ch)
#pragma unroll
        for (int j = 0; j < 4; ++j) {
            float e0 = __expf(-((float)v0[ch][j] - mn0[j]) * inv0[j]);
            float e1 = __expf(-((float)v1[ch][j] - mn1[j]) * inv1[j]);
            float df = e0 - e1;
            acc += df * df;
        }

#pragma unroll
    for (int off = 32; off > 0; off >>= 1)
        acc += __shfl_down(acc, off, 64);
    __shared__ float smem[4];
    int lane = threadIdx.x & 63, wv = threadIdx.x >> 6;
    if (lane == 0) smem[wv] = acc;
    __syncthreads();
    if (threadIdx.x == 0)
        partial[blockIdx.x] = smem[0] + smem[1] + smem[2] + smem[3];
}

// kred: sum 2048 partials, write the final scalar.
__global__ __launch_bounds__(256) void kred(const float* __restrict__ partial,
                                            float* __restrict__ out) {
    int tid = threadIdx.x;
    float acc = 0.0f;
#pragma unroll
    for (int k = 0; k < 8; ++k)
        acc += partial[tid + (k << 8)];
#pragma unroll
    for (int off = 32; off > 0; off >>= 1)
        acc += __shfl_down(acc, off, 64);
    __shared__ float smem[4];
    int lane = tid & 63, wv = tid >> 6;
    if (lane == 0) smem[wv] = acc;
    __syncthreads();
    if (tid == 0)
        out[0] = (smem[0] + smem[1] + smem[2] + smem[3])
               * (1.0f / (12.0f * (float)VOX));
}

__global__ void kdiag(float* out, float ws_mb) { out[0] = ws_mb; }

extern "C" void kernel_launch(void* const* d_in, const int* in_sizes, int n_in,
                              void* d_out, int out_size, void* d_ws, size_t ws_size,
                              hipStream_t stream) {
    const float* y_true = (const float*)d_in[0];
    const float* y_pred = (const float*)d_in[1];
    float* out = (float*)d_out;

    const size_t NEED = 2ull * IMGS * sizeof(_Float16) + 8192 + 64;  // ~96.2 MB
    if (ws_size < NEED) {
        kdiag<<<1, 1, 0, stream>>>(out, (float)(ws_size >> 20));
        return;
    }

    _Float16* S0      = (_Float16*)d_ws;            // ssd img0 (padded layout)
    _Float16* S1      = S0 + (size_t)IMGS;          // ssd img1
    float*    partial = (float*)(S1 + (size_t)IMGS);// 2048 floats

    // 3072 wave-tasks per image (12 ch x 16 hslices x 16 dsegs), 4 waves/block
    f123<<<dim3(768, 2), 256, 0, stream>>>(y_true, y_pred, S0);
    kmse<<<VOX / 4 / 256, 256, 0, stream>>>(S0, S1, partial);
    kred<<<1, 256, 0, stream>>>(partial, out);
}

// Round 4
// 137.632 us; speedup vs baseline: 1.6453x; 1.1539x over previous
//
#include <hip/hip_runtime.h>

#define DIM   128
#define DMASK 127
#define PLANE (DIM * DIM)     // 16384
#define VOX   (1 << 21)       // 128^3
#define NCH   12

// De-aliased layout (validated r12: 199->142 us): channel stride 4MB+4KB,
// image stride +2KB more. Keeps the 24 stream bases off one channel slot.
#define CHS   (VOX + 2048)
#define IMGS  (NCH * CHS + 1024)

typedef __attribute__((ext_vector_type(2))) _Float16 half2v;
typedef __attribute__((ext_vector_type(4))) _Float16 half4v;
typedef __attribute__((ext_vector_type(8))) _Float16 half8v;

// Per-channel shift pairs (d,h,w) = 2*(one_hot_idx - 1); verified (absmax 0).
__constant__ int c_sd1[12] = { 0, 0, 0, 0, 0, 2, 2, 2, 0, 0, 0, 0};
__constant__ int c_sh1[12] = { 0,-2,-2, 0, 0, 0, 0, 0, 2, 2, 2, 2};
__constant__ int c_sw1[12] = {-2, 0, 0, 2, 2, 0, 0, 0, 0, 0, 0, 0};
__constant__ int c_sd2[12] = {-2,-2, 0,-2, 0, 0, 0, 0,-2, 0, 0, 2};
__constant__ int c_sh2[12] = { 0, 0, 0, 0,-2, 0,-2, 0, 0, 0, 0, 0};
__constant__ int c_sw2[12] = { 0, 0,-2, 0, 0,-2, 0, 2, 0,-2, 2, 0};

__device__ __forceinline__ int clamp7(int v) { return min(max(v, 0), DMASK); }

// F123 v5 (RESTORED r0 verbatim — measured 66-70 us, FETCH~23MB, WRITE=output).
// r1: launch_bounds(256,4) spilled (64 VGPR cap). r3: finer 8-plane d-segs
// doubled HBM bytes (FETCH 23->82MB, WRITE +60MB) with no occupancy gain.
// 16-plane d-segs + (256,3) is the validated optimum of this structure.
// Each wave owns (ch, 8-row h-slice, 16-plane d-seg); W-box via lane
// shuffles, H-box via register sliding sums, D-box via register window.
// ZERO LDS, ZERO __syncthreads.
__global__ __launch_bounds__(256, 3) void f123(const float* __restrict__ img0,
                                               const float* __restrict__ img1,
                                               _Float16* __restrict__ Sall) {
    const float* img = blockIdx.y ? img1 : img0;
    _Float16* outS = Sall + (size_t)blockIdx.y * IMGS;
    const char* imgc = (const char*)img;

    int wid = (blockIdx.x << 2) + (threadIdx.x >> 6);  // 0..1535
    int ch = wid >> 7;                 // 12
    int hs = (wid >> 3) & 15;          // 16 h-slices of 8 rows
    int ds = wid & 7;                  // 8 d-segs of 16 planes
    int h0 = hs << 3;
    int d0 = ds << 4;
    int l  = threadIdx.x & 63;

    int sd1 = c_sd1[ch], sh1 = c_sh1[ch], sw1 = c_sw1[ch];
    int sd2 = c_sd2[ch], sh2 = c_sh2[ch], sw2 = c_sw2[ch];

    // wave-uniform row byte-offsets (double clamp composed), 12 rows
    int rowOffA[12], rowOffB[12];
#pragma unroll
    for (int r = 0; r < 12; ++r) {
        int hq = clamp7(h0 - 2 + r);
        rowOffA[r] = clamp7(hq + sh1) * (DIM * 4);
        rowOffB[r] = clamp7(hq + sh2) * (DIM * 4);
    }

    // per-lane column byte bases (float2 at cols 2l+sw, clamped to [0,126])
    int c2 = l << 1;
    int colA = min(max(c2 + sw1, 0), 126) * 4;
    int colB = min(max(c2 + sw2, 0), 126) * 4;
    bool fixAlo = (sw1 < 0) && (l == 0);   // need (v0,v0): a.y = a.x
    bool fixAhi = (sw1 > 0) && (l == 63);  // need (v127,v127): a.x = a.y
    bool fixBlo = (sw2 < 0) && (l == 0);
    bool fixBhi = (sw2 > 0) && (l == 63);

    float2 win[8];
    half2v hist[5][8];
#pragma unroll
    for (int k = 0; k < 8; ++k) {
        win[k].x = 0.0f; win[k].y = 0.0f;
#pragma unroll
        for (int s = 0; s < 5; ++s) hist[s][k] = half2v{(_Float16)0.0f, (_Float16)0.0f};
    }

    _Float16* dstBase = outS + (size_t)ch * CHS + h0 * DIM + c2;

    for (int oo = 0; oo < 4; ++oo) {
#pragma unroll
        for (int s5 = 0; s5 < 5; ++s5) {
            int it = oo * 5 + s5;
            int dp = clamp7(d0 - 2 + it);
            int pOffA = clamp7(dp + sd1) * (PLANE * 4);
            int pOffB = clamp7(dp + sd2) * (PLANE * 4);

            float tX[12], tY[12];
#pragma unroll
            for (int r = 0; r < 12; ++r) {
                float2 a = *(const float2*)(imgc + (pOffA + rowOffA[r] + colA));
                float2 b = *(const float2*)(imgc + (pOffB + rowOffB[r] + colB));
                a.y = fixAlo ? a.x : a.y;  a.x = fixAhi ? a.y : a.x;
                b.y = fixBlo ? b.x : b.y;  b.x = fixBhi ? b.y : b.x;
                float dx = a.x - b.x; dx *= dx;      // D2[2l]
                float dy = a.y - b.y; dy *= dy;      // D2[2l+1]
                float lx = __shfl_up(dx, 1, 64);     // D2[2l-2] (lane0: own dx = replicate OK)
                float ly = __shfl_up(dy, 1, 64);     // D2[2l-1]
                float rx = __shfl_down(dx, 1, 64);   // D2[2l+2]
                float ry = __shfl_down(dy, 1, 64);   // D2[2l+3] (lane63: own dy = replicate OK)
                ly = (l == 0)  ? dx : ly;            // D2[-1 -> 0]
                rx = (l == 63) ? dy : rx;            // D2[128 -> 127]
                tX[r] = lx + ly + dx + dy + rx;      // W-box(2l)
                tY[r] = ly + dx + dy + rx + ry;      // W-box(2l+1)
            }

            // H-box sliding 5-row sums + D-window update
            float sx = tX[0] + tX[1] + tX[2] + tX[3] + tX[4];
            float sy = tY[0] + tY[1] + tY[2] + tY[3] + tY[4];
            bool dowrite = (it >= 4);
            _Float16* dstD = dstBase + (size_t)(d0 + it - 4) * PLANE;
#pragma unroll
            for (int k = 0; k < 8; ++k) {
                half2v hv = { (_Float16)sx, (_Float16)sy };  // round first (validated)
                half2v old = hist[s5][k];
                win[k].x += (float)hv[0] - (float)old[0];
                win[k].y += (float)hv[1] - (float)old[1];
                hist[s5][k] = hv;
                if (dowrite) {
                    half2v ov = { (_Float16)win[k].x, (_Float16)win[k].y };
                    *(half2v*)(dstD + k * DIM) = ov;
                }
                if (k < 7) {
                    sx += tX[k + 5] - tX[k];
                    sy += tY[k + 5] - tY[k];
                }
            }
        }
    }
}

// kmse v7: 8 vox/thread, 24 independent 16-B half8 loads (coalescing sweet
// spot: 1 KiB/wave-instr), all-register, no atomics, de-aliased CHS stride.
// r4 theory: kmse was ~55us for 201MB (3.5 TB/s) with 8-B loads; 16-B loads
// halve the load-instr count. ~140-160 VGPR live -> bounds(256,2) for spill
// headroom (r1 lesson: never squeeze the allocator).
__global__ __launch_bounds__(256, 2) void kmse(const _Float16* __restrict__ S0,
                                               const _Float16* __restrict__ S1,
                                               float* __restrict__ partial) {
    int t = blockIdx.x * 256 + threadIdx.x;       // 1024 blocks

    half8v v0[NCH], v1[NCH];
#pragma unroll
    for (int ch = 0; ch < NCH; ++ch)
        v0[ch] = ((const half8v*)(S0 + (size_t)ch * CHS))[t];
#pragma unroll
    for (int ch = 0; ch < NCH; ++ch)
        v1[ch] = ((const half8v*)(S1 + (size_t)ch * CHS))[t];

    float mn0[8], sm0[8], mn1[8], sm1[8];
#pragma unroll
    for (int j = 0; j < 8; ++j) {
        mn0[j] = 3.4e38f; sm0[j] = 0.0f;
        mn1[j] = 3.4e38f; sm1[j] = 0.0f;
    }
#pragma unroll
    for (int ch = 0; ch < NCH; ++ch)
#pragma unroll
        for (int j = 0; j < 8; ++j) {
            float s0 = (float)v0[ch][j];
            float s1 = (float)v1[ch][j];
            mn0[j] = fminf(mn0[j], s0); sm0[j] += s0;
            mn1[j] = fminf(mn1[j], s1); sm1[j] += s1;
        }

    float inv0[8], inv1[8];
#pragma unroll
    for (int j = 0; j < 8; ++j) {
        inv0[j] = __fdividef(1.0f, sm0[j] * (1.0f / 12.0f) - mn0[j]);
        inv1[j] = __fdividef(1.0f, sm1[j] * (1.0f / 12.0f) - mn1[j]);
    }

    float acc = 0.0f;
#pragma unroll
    for (int ch = 0; ch < NCH; ++ch)
#pragma unroll
        for (int j = 0; j < 8; ++j) {
            float e0 = __expf(-((float)v0[ch][j] - mn0[j]) * inv0[j]);
            float e1 = __expf(-((float)v1[ch][j] - mn1[j]) * inv1[j]);
            float df = e0 - e1;
            acc += df * df;
        }

#pragma unroll
    for (int off = 32; off > 0; off >>= 1)
        acc += __shfl_down(acc, off, 64);
    __shared__ float smem[4];
    int lane = threadIdx.x & 63, wv = threadIdx.x >> 6;
    if (lane == 0) smem[wv] = acc;
    __syncthreads();
    if (threadIdx.x == 0)
        partial[blockIdx.x] = smem[0] + smem[1] + smem[2] + smem[3];
}

// kred: sum 1024 partials, write the final scalar.
__global__ __launch_bounds__(256) void kred(const float* __restrict__ partial,
                                            float* __restrict__ out) {
    int tid = threadIdx.x;
    float acc = 0.0f;
#pragma unroll
    for (int k = 0; k < 4; ++k)
        acc += partial[tid + (k << 8)];
#pragma unroll
    for (int off = 32; off > 0; off >>= 1)
        acc += __shfl_down(acc, off, 64);
    __shared__ float smem[4];
    int lane = tid & 63, wv = tid >> 6;
    if (lane == 0) smem[wv] = acc;
    __syncthreads();
    if (tid == 0)
        out[0] = (smem[0] + smem[1] + smem[2] + smem[3])
               * (1.0f / (12.0f * (float)VOX));
}

__global__ void kdiag(float* out, float ws_mb) { out[0] = ws_mb; }

extern "C" void kernel_launch(void* const* d_in, const int* in_sizes, int n_in,
                              void* d_out, int out_size, void* d_ws, size_t ws_size,
                              hipStream_t stream) {
    const float* y_true = (const float*)d_in[0];
    const float* y_pred = (const float*)d_in[1];
    float* out = (float*)d_out;

    const size_t NEED = 2ull * IMGS * sizeof(_Float16) + 8192 + 64;  // ~96.2 MB
    if (ws_size < NEED) {
        kdiag<<<1, 1, 0, stream>>>(out, (float)(ws_size >> 20));
        return;
    }

    _Float16* S0      = (_Float16*)d_ws;            // ssd img0 (padded layout)
    _Float16* S1      = S0 + (size_t)IMGS;          // ssd img1
    float*    partial = (float*)(S1 + (size_t)IMGS);// 1024 floats

    // 1536 wave-tasks per image (12 ch x 16 hslices x 8 dsegs), 4 waves/block
    f123<<<dim3(384, 2), 256, 0, stream>>>(y_true, y_pred, S0);
    kmse<<<VOX / 8 / 256, 256, 0, stream>>>(S0, S1, partial);
    kred<<<1, 256, 0, stream>>>(partial, out);
}

// Round 5
// 129.561 us; speedup vs baseline: 1.7478x; 1.0623x over previous
//
#include <hip/hip_runtime.h>

#define DIM   128
#define DMASK 127
#define PLANE (DIM * DIM)     // 16384
#define VOX   (1 << 21)       // 128^3
#define NCH   12

// De-aliased layout (validated r12: 199->142 us): channel stride 4MB+4KB,
// image stride +2KB more. Keeps the 24 stream bases off one channel slot.
#define CHS   (VOX + 2048)
#define IMGS  (NCH * CHS + 1024)

typedef __attribute__((ext_vector_type(2))) _Float16 half2v;
typedef __attribute__((ext_vector_type(4))) _Float16 half4v;

// Per-channel shift pairs (d,h,w) = 2*(one_hot_idx - 1); verified (absmax 0).
__constant__ int c_sd1[12] = { 0, 0, 0, 0, 0, 2, 2, 2, 0, 0, 0, 0};
__constant__ int c_sh1[12] = { 0,-2,-2, 0, 0, 0, 0, 0, 2, 2, 2, 2};
__constant__ int c_sw1[12] = {-2, 0, 0, 2, 2, 0, 0, 0, 0, 0, 0, 0};
__constant__ int c_sd2[12] = {-2,-2, 0,-2, 0, 0, 0, 0,-2, 0, 0, 2};
__constant__ int c_sh2[12] = { 0, 0, 0, 0,-2, 0,-2, 0, 0, 0, 0, 0};
__constant__ int c_sw2[12] = { 0, 0,-2, 0, 0,-2, 0, 2, 0,-2, 2, 0};

__device__ __forceinline__ int clamp7(int v) { return min(max(v, 0), DMASK); }

// F123 v5b: r0 structure (validated 66-70 us) + add-factoring (8->5 adds/row).
// Session ledger: r1 bounds(256,4) -> 64-VGPR spill disaster; r3 finer 8-plane
// d-segs -> HBM x2 (FETCH 23->82MB) with no occupancy gain. 16-plane d-segs +
// (256,3) + natural 84 VGPR is the optimum of this structure.
// Each wave owns (ch, 8-row h-slice, 16-plane d-seg); W-box via lane
// shuffles, H-box via register sliding sums, D-box via register window.
// ZERO LDS, ZERO __syncthreads.
__global__ __launch_bounds__(256, 3) void f123(const float* __restrict__ img0,
                                               const float* __restrict__ img1,
                                               _Float16* __restrict__ Sall) {
    const float* img = blockIdx.y ? img1 : img0;
    _Float16* outS = Sall + (size_t)blockIdx.y * IMGS;
    const char* imgc = (const char*)img;

    int wid = (blockIdx.x << 2) + (threadIdx.x >> 6);  // 0..1535
    int ch = wid >> 7;                 // 12
    int hs = (wid >> 3) & 15;          // 16 h-slices of 8 rows
    int ds = wid & 7;                  // 8 d-segs of 16 planes
    int h0 = hs << 3;
    int d0 = ds << 4;
    int l  = threadIdx.x & 63;

    int sd1 = c_sd1[ch], sh1 = c_sh1[ch], sw1 = c_sw1[ch];
    int sd2 = c_sd2[ch], sh2 = c_sh2[ch], sw2 = c_sw2[ch];

    // wave-uniform row byte-offsets (double clamp composed), 12 rows
    int rowOffA[12], rowOffB[12];
#pragma unroll
    for (int r = 0; r < 12; ++r) {
        int hq = clamp7(h0 - 2 + r);
        rowOffA[r] = clamp7(hq + sh1) * (DIM * 4);
        rowOffB[r] = clamp7(hq + sh2) * (DIM * 4);
    }

    // per-lane column byte bases (float2 at cols 2l+sw, clamped to [0,126])
    int c2 = l << 1;
    int colA = min(max(c2 + sw1, 0), 126) * 4;
    int colB = min(max(c2 + sw2, 0), 126) * 4;
    bool fixAlo = (sw1 < 0) && (l == 0);   // need (v0,v0): a.y = a.x
    bool fixAhi = (sw1 > 0) && (l == 63);  // need (v127,v127): a.x = a.y
    bool fixBlo = (sw2 < 0) && (l == 0);
    bool fixBhi = (sw2 > 0) && (l == 63);

    float2 win[8];
    half2v hist[5][8];
#pragma unroll
    for (int k = 0; k < 8; ++k) {
        win[k].x = 0.0f; win[k].y = 0.0f;
#pragma unroll
        for (int s = 0; s < 5; ++s) hist[s][k] = half2v{(_Float16)0.0f, (_Float16)0.0f};
    }

    _Float16* dstBase = outS + (size_t)ch * CHS + h0 * DIM + c2;

    for (int oo = 0; oo < 4; ++oo) {
#pragma unroll
        for (int s5 = 0; s5 < 5; ++s5) {
            int it = oo * 5 + s5;
            int dp = clamp7(d0 - 2 + it);
            int pOffA = clamp7(dp + sd1) * (PLANE * 4);
            int pOffB = clamp7(dp + sd2) * (PLANE * 4);

            float tX[12], tY[12];
#pragma unroll
            for (int r = 0; r < 12; ++r) {
                float2 a = *(const float2*)(imgc + (pOffA + rowOffA[r] + colA));
                float2 b = *(const float2*)(imgc + (pOffB + rowOffB[r] + colB));
                a.y = fixAlo ? a.x : a.y;  a.x = fixAhi ? a.y : a.x;
                b.y = fixBlo ? b.x : b.y;  b.x = fixBhi ? b.y : b.x;
                float dx = a.x - b.x; dx *= dx;      // D2[2l]
                float dy = a.y - b.y; dy *= dy;      // D2[2l+1]
                float lx = __shfl_up(dx, 1, 64);     // D2[2l-2] (lane0: own dx = replicate OK)
                float ly = __shfl_up(dy, 1, 64);     // D2[2l-1]
                float rx = __shfl_down(dx, 1, 64);   // D2[2l+2]
                float ry = __shfl_down(dy, 1, 64);   // D2[2l+3] (lane63: own dy = replicate OK)
                ly = (l == 0)  ? dx : ly;            // D2[-1 -> 0]
                rx = (l == 63) ? dy : rx;            // D2[128 -> 127]
                float m = ly + dx + dy + rx;         // shared middle (r4: 8->5 adds)
                tX[r] = lx + m;                      // W-box(2l)
                tY[r] = m + ry;                      // W-box(2l+1)
            }

            // H-box sliding 5-row sums + D-window update
            float sx = tX[0] + tX[1] + tX[2] + tX[3] + tX[4];
            float sy = tY[0] + tY[1] + tY[2] + tY[3] + tY[4];
            bool dowrite = (it >= 4);
            _Float16* dstD = dstBase + (size_t)(d0 + it - 4) * PLANE;
#pragma unroll
            for (int k = 0; k < 8; ++k) {
                half2v hv = { (_Float16)sx, (_Float16)sy };  // round first (validated)
                half2v old = hist[s5][k];
                win[k].x += (float)hv[0] - (float)old[0];
                win[k].y += (float)hv[1] - (float)old[1];
                hist[s5][k] = hv;
                if (dowrite) {
                    half2v ov = { (_Float16)win[k].x, (_Float16)win[k].y };
                    *(half2v*)(dstD + k * DIM) = ov;
                }
                if (k < 7) {
                    sx += tX[k + 5] - tX[k];
                    sy += tY[k + 5] - tY[k];
                }
            }
        }
    }
}

// kmse v6 (REVERTED to validated r0 config; r4's half8/8-vox variant was ~6us
// slower: ~150 live VGPRs crossed the 128 occupancy step -> 2 waves/SIMD).
// 4 vox/thread, 24 independent 8-B loads, all-register, no atomics.
__global__ __launch_bounds__(256, 3) void kmse(const _Float16* __restrict__ S0,
                                               const _Float16* __restrict__ S1,
                                               float* __restrict__ partial) {
    int t = blockIdx.x * 256 + threadIdx.x;       // 2048 blocks

    half4v v0[NCH], v1[NCH];
#pragma unroll
    for (int ch = 0; ch < NCH; ++ch)
        v0[ch] = ((const half4v*)(S0 + (size_t)ch * CHS))[t];
#pragma unroll
    for (int ch = 0; ch < NCH; ++ch)
        v1[ch] = ((const half4v*)(S1 + (size_t)ch * CHS))[t];

    float mn0[4], sm0[4], mn1[4], sm1[4];
#pragma unroll
    for (int j = 0; j < 4; ++j) {
        mn0[j] = 3.4e38f; sm0[j] = 0.0f;
        mn1[j] = 3.4e38f; sm1[j] = 0.0f;
    }
#pragma unroll
    for (int ch = 0; ch < NCH; ++ch)
#pragma unroll
        for (int j = 0; j < 4; ++j) {
            float s0 = (float)v0[ch][j];
            float s1 = (float)v1[ch][j];
            mn0[j] = fminf(mn0[j], s0); sm0[j] += s0;
            mn1[j] = fminf(mn1[j], s1); sm1[j] += s1;
        }

    float inv0[4], inv1[4];
#pragma unroll
    for (int j = 0; j < 4; ++j) {
        inv0[j] = __fdividef(1.0f, sm0[j] * (1.0f / 12.0f) - mn0[j]);
        inv1[j] = __fdividef(1.0f, sm1[j] * (1.0f / 12.0f) - mn1[j]);
    }

    float acc = 0.0f;
#pragma unroll
    for (int ch = 0; ch < NCH; ++ch)
#pragma unroll
        for (int j = 0; j < 4; ++j) {
            float e0 = __expf(-((float)v0[ch][j] - mn0[j]) * inv0[j]);
            float e1 = __expf(-((float)v1[ch][j] - mn1[j]) * inv1[j]);
            float df = e0 - e1;
            acc += df * df;
        }

#pragma unroll
    for (int off = 32; off > 0; off >>= 1)
        acc += __shfl_down(acc, off, 64);
    __shared__ float smem[4];
    int lane = threadIdx.x & 63, wv = threadIdx.x >> 6;
    if (lane == 0) smem[wv] = acc;
    __syncthreads();
    if (threadIdx.x == 0)
        partial[blockIdx.x] = smem[0] + smem[1] + smem[2] + smem[3];
}

// kred: sum 2048 partials, write the final scalar.
__global__ __launch_bounds__(256) void kred(const float* __restrict__ partial,
                                            float* __restrict__ out) {
    int tid = threadIdx.x;
    float acc = 0.0f;
#pragma unroll
    for (int k = 0; k < 8; ++k)
        acc += partial[tid + (k << 8)];
#pragma unroll
    for (int off = 32; off > 0; off >>= 1)
        acc += __shfl_down(acc, off, 64);
    __shared__ float smem[4];
    int lane = tid & 63, wv = tid >> 6;
    if (lane == 0) smem[wv] = acc;
    __syncthreads();
    if (tid == 0)
        out[0] = (smem[0] + smem[1] + smem[2] + smem[3])
               * (1.0f / (12.0f * (float)VOX));
}

__global__ void kdiag(float* out, float ws_mb) { out[0] = ws_mb; }

extern "C" void kernel_launch(void* const* d_in, const int* in_sizes, int n_in,
                              void* d_out, int out_size, void* d_ws, size_t ws_size,
                              hipStream_t stream) {
    const float* y_true = (const float*)d_in[0];
    const float* y_pred = (const float*)d_in[1];
    float* out = (float*)d_out;

    const size_t NEED = 2ull * IMGS * sizeof(_Float16) + 8192 + 64;  // ~96.2 MB
    if (ws_size < NEED) {
        kdiag<<<1, 1, 0, stream>>>(out, (float)(ws_size >> 20));
        return;
    }

    _Float16* S0      = (_Float16*)d_ws;            // ssd img0 (padded layout)
    _Float16* S1      = S0 + (size_t)IMGS;          // ssd img1
    float*    partial = (float*)(S1 + (size_t)IMGS);// 2048 floats

    // 1536 wave-tasks per image (12 ch x 16 hslices x 8 dsegs), 4 waves/block
    f123<<<dim3(384, 2), 256, 0, stream>>>(y_true, y_pred, S0);
    kmse<<<VOX / 4 / 256, 256, 0, stream>>>(S0, S1, partial);
    kred<<<1, 256, 0, stream>>>(partial, out);
}